// Round 7
// baseline (44.791 us; speedup 1.0000x reference)
//
#include <hip/hip_runtime.h>
#include <stdint.h>

#define NF    64
#define DIM0  50000
#define SROWS 100000
#define TPB   256
#define QPT   2
#define COEF_OFF_BYTES (SROWS * 32)   // coef table after 3.2MB of codes

typedef float    f32x4 __attribute__((ext_vector_type(4)));
typedef uint32_t u32x4 __attribute__((ext_vector_type(4)));

// ---------------------------------------------------------------------------
// Pass 1: closed-form quantize (row = 32B, 64 x 4-bit codes) + coef table.
//   q = clamp(ceil(16*f - 1), 0, 15)   (bit-exact vs jnp.argmin, tie->lower;
//   validated rounds 2-6, absmax <= 2.4e-7)
// Codes stored nontemporally: the L2 they'd dirty is invalidated at the
// kernel boundary anyway; stream them to L3 and skip the writeback flush.
// Block 0 wave 0 derives per-feature coefficients:
//   W'=W/256, X'=W/512+X/16, Y'=W/512+Y/16, C=W/1024+(X+Y)/32+V3
//   (W=V0-V1-V2+V3, X=V1-V3, Y=V2-V3), plus per-half constant sums Ca,Cb.
// ---------------------------------------------------------------------------
__global__ void quantize_kernel(const float* __restrict__ feats,
                                const float* __restrict__ values,
                                uint32_t* __restrict__ qcodes,
                                float* __restrict__ coef) {
    int t = threadIdx.x;
    if (blockIdx.x == 0 && t < NF) {
        float v0 = values[t], v1 = values[NF + t];
        float v2 = values[2 * NF + t], v3 = values[3 * NF + t];
        float W = v0 - v1 - v2 + v3;
        float X = v1 - v3, Y = v2 - v3;
        float Wp = W * (1.0f / 256.0f);
        float Xp = W * (1.0f / 512.0f) + X * (1.0f / 16.0f);
        float Yp = W * (1.0f / 512.0f) + Y * (1.0f / 16.0f);
        float C  = W * (1.0f / 1024.0f) + (X + Y) * (1.0f / 32.0f) + v3;
        ((f32x4*)coef)[t] = (f32x4){Wp, Xp, Yp, C};
        float Cs = C;
        Cs += __shfl_xor(Cs, 1);  Cs += __shfl_xor(Cs, 2);
        Cs += __shfl_xor(Cs, 4);  Cs += __shfl_xor(Cs, 8);
        Cs += __shfl_xor(Cs, 16);
        if (t == 0)  coef[NF * 4 + 0] = Cs;
        if (t == 32) coef[NF * 4 + 1] = Cs;
    }

    int gid = blockIdx.x * blockDim.x + t;   // word idx = s*8+w (exact grid)
    const f32x4* fr = (const f32x4*)(feats + (size_t)gid * 8);
    f32x4 fA = __builtin_nontemporal_load(fr);
    f32x4 fB = __builtin_nontemporal_load(fr + 1);
    float fv[8] = {fA.x, fA.y, fA.z, fA.w, fB.x, fB.y, fB.z, fB.w};

    uint32_t word = 0u;
#pragma unroll
    for (int j = 0; j < 8; ++j) {
        float x = fmaf(fv[j], 16.0f, -1.0f);   // exact: 16f-1 representable
        int q = (int)ceilf(x);
        q = q < 0 ? 0 : (q > 15 ? 15 : q);
        word |= (uint32_t)q << (4 * j);
    }
    __builtin_nontemporal_store(word, qcodes + gid);
}

// ---------------------------------------------------------------------------
// Pass 2: 2 queries/thread; all 8 gather loads (4 lines... 2 lines/query)
// issued before any compute for max memory-level parallelism.
//   per feature (7 ops): h = fma(W',B,X'); acc1 = fma(A,h,acc1);
//                        acc2 = fma(Y',B,acc2)
//   asum = acc1a+acc2a+Ca ; bsum = acc1b+acc2b+Cb
//   out  = asum * tanh(bsum) * exp(scale) + bias
// Coefs via uniform-address s_load (scalar cache), no LDS in inner loop.
// ---------------------------------------------------------------------------
__global__ __launch_bounds__(TPB) void query_kernel(
        const uint32_t* __restrict__ qcodes,
        const f32x4* __restrict__ coef,
        const float* __restrict__ scale,
        const float* __restrict__ bias,
        const int* __restrict__ idx0,
        const int* __restrict__ idx1,
        float* __restrict__ out, int N) {
    int t = threadIdx.x;
    int base = blockIdx.x * (TPB * QPT) + t;

    // ---- issue all gathers first ----
    uint32_t aw[QPT][8], bw[QPT][8];
#pragma unroll
    for (int k = 0; k < QPT; ++k) {
        int n = base + k * TPB;
        int m = n < N ? n : N - 1;
        int r0 = __builtin_nontemporal_load(idx0 + m);
        int r1 = DIM0 + __builtin_nontemporal_load(idx1 + m);
        const u32x4* pa = (const u32x4*)(qcodes + (size_t)r0 * 8);
        const u32x4* pb = (const u32x4*)(qcodes + (size_t)r1 * 8);
        u32x4 x0 = pa[0], x1 = pa[1];
        u32x4 y0 = pb[0], y1 = pb[1];
        aw[k][0] = x0.x; aw[k][1] = x0.y; aw[k][2] = x0.z; aw[k][3] = x0.w;
        aw[k][4] = x1.x; aw[k][5] = x1.y; aw[k][6] = x1.z; aw[k][7] = x1.w;
        bw[k][0] = y0.x; bw[k][1] = y0.y; bw[k][2] = y0.z; bw[k][3] = y0.w;
        bw[k][4] = y1.x; bw[k][5] = y1.y; bw[k][6] = y1.z; bw[k][7] = y1.w;
    }

    // ---- contraction: 7 VALU ops per feature per query ----
    float a1[QPT] = {0.f, 0.f};   // sum over f<32 of A*(W'B+X') + Y'B
    float b1[QPT] = {0.f, 0.f};   // sum over f>=32
#pragma unroll
    for (int wd = 0; wd < 8; ++wd) {
#pragma unroll
        for (int j = 0; j < 8; ++j) {
            int f = wd * 8 + j;
            f32x4 c = coef[f];                       // uniform -> s_load
#pragma unroll
            for (int k = 0; k < QPT; ++k) {
                float A = (float)((aw[k][wd] >> (4 * j)) & 15u);
                float B = (float)((bw[k][wd] >> (4 * j)) & 15u);
                float h = fmaf(c.x, B, c.y);         // W'*B + X'
                float g = fmaf(c.z, B, (wd < 4 ? a1[k] : b1[k]));
                if (wd < 4) a1[k] = fmaf(A, h, g);
                else        b1[k] = fmaf(A, h, g);
            }
        }
    }

    const float* cs = (const float*)coef;
    float Ca = cs[NF * 4 + 0];
    float Cb = cs[NF * 4 + 1];
    float es = expf(scale[0]);
    float bi = bias[0];
#pragma unroll
    for (int k = 0; k < QPT; ++k) {
        int n = base + k * TPB;
        if (n < N) {
            float asum = a1[k] + Ca;
            float bsum = b1[k] + Cb;
            __builtin_nontemporal_store(asum * tanhf(bsum) * es + bi, out + n);
        }
    }
}

extern "C" void kernel_launch(void* const* d_in, const int* in_sizes, int n_in,
                              void* d_out, int out_size, void* d_ws, size_t ws_size,
                              hipStream_t stream) {
    const float* values = (const float*)d_in[0];  // [1,4,64]
    const float* feats  = (const float*)d_in[1];  // [100000,64]
    const float* scale  = (const float*)d_in[3];  // [1]
    const float* bias   = (const float*)d_in[4];  // [1]
    const int*   idx0   = (const int*)d_in[5];    // [N]
    const int*   idx1   = (const int*)d_in[6];    // [N]
    float*       out    = (float*)d_out;          // [N] f32

    uint32_t* qcodes = (uint32_t*)d_ws;                          // 3.2 MB
    float*    coef   = (float*)((char*)d_ws + COEF_OFF_BYTES);   // 64*4+2 floats

    int nwords = SROWS * 8;                       // 800000 = 3125 * 256 exact
    quantize_kernel<<<nwords / TPB, TPB, 0, stream>>>(feats, values, qcodes, coef);

    int N = out_size;
    int qblocks = (N + TPB * QPT - 1) / (TPB * QPT);
    query_kernel<<<qblocks, TPB, 0, stream>>>(
        qcodes, (const f32x4*)coef, scale, bias, idx0, idx1, out, N);
}

// Round 8
// 36.891 us; speedup vs baseline: 1.2141x; 1.2141x over previous
//
#include <hip/hip_runtime.h>
#include <stdint.h>

#define NF    64
#define DIM0  50000
#define SROWS 100000
#define TPB   256
#define COEF_OFF_BYTES (SROWS * 32)   // coef table after 3.2MB of codes

typedef float    f32x4 __attribute__((ext_vector_type(4)));
typedef uint32_t u32x4 __attribute__((ext_vector_type(4)));

// ---------------------------------------------------------------------------
// Pass 1: closed-form quantize (row = 32B, 64 x 4-bit codes) + coef table.
//   q = clamp(ceil(16*f - 1), 0, 15)   (bit-exact vs jnp.argmin, tie->lower;
//   validated rounds 2-7, absmax <= 2.4e-7)
// Identical to round 6 (plain code store — nontemporal store regressed r7).
// Block 0 wave 0 derives per-feature coefficients:
//   W'=W/256, X'=W/512+X/16, Y'=W/512+Y/16, C=W/1024+(X+Y)/32+V3
//   (W=V0-V1-V2+V3, X=V1-V3, Y=V2-V3), plus per-half constant sums Ca,Cb.
// ---------------------------------------------------------------------------
__global__ void quantize_kernel(const float* __restrict__ feats,
                                const float* __restrict__ values,
                                uint32_t* __restrict__ qcodes,
                                float* __restrict__ coef) {
    int t = threadIdx.x;
    if (blockIdx.x == 0 && t < NF) {
        float v0 = values[t], v1 = values[NF + t];
        float v2 = values[2 * NF + t], v3 = values[3 * NF + t];
        float W = v0 - v1 - v2 + v3;
        float X = v1 - v3, Y = v2 - v3;
        float Wp = W * (1.0f / 256.0f);
        float Xp = W * (1.0f / 512.0f) + X * (1.0f / 16.0f);
        float Yp = W * (1.0f / 512.0f) + Y * (1.0f / 16.0f);
        float C  = W * (1.0f / 1024.0f) + (X + Y) * (1.0f / 32.0f) + v3;
        ((f32x4*)coef)[t] = (f32x4){Wp, Xp, Yp, C};
        float Cs = C;
        Cs += __shfl_xor(Cs, 1);  Cs += __shfl_xor(Cs, 2);
        Cs += __shfl_xor(Cs, 4);  Cs += __shfl_xor(Cs, 8);
        Cs += __shfl_xor(Cs, 16);
        if (t == 0)  coef[NF * 4 + 0] = Cs;
        if (t == 32) coef[NF * 4 + 1] = Cs;
    }

    int gid = blockIdx.x * blockDim.x + t;   // word idx = s*8+w (exact grid)
    const f32x4* fr = (const f32x4*)(feats + (size_t)gid * 8);
    f32x4 fA = __builtin_nontemporal_load(fr);
    f32x4 fB = __builtin_nontemporal_load(fr + 1);
    float fv[8] = {fA.x, fA.y, fA.z, fA.w, fB.x, fB.y, fB.z, fB.w};

    uint32_t word = 0u;
#pragma unroll
    for (int j = 0; j < 8; ++j) {
        float x = fmaf(fv[j], 16.0f, -1.0f);   // exact: 16f-1 representable
        int q = (int)ceilf(x);
        q = q < 0 ? 0 : (q > 15 ? 15 : q);
        word |= (uint32_t)q << (4 * j);
    }
    qcodes[gid] = word;
}

// ---------------------------------------------------------------------------
// Pass 2: lane-pair per query. Lanes l and l+32 own query q = base + (l&31);
// lane-half h = l>>5 loads bytes [16h,16h+16) of BOTH rows (one 16B load per
// row) and accumulates feature-half h. Per gather instruction, lanes l/l+32
// address the same 64B line (rows are 32B, line-aligned) -> 32 distinct
// lines per instruction instead of 64, and 2 gather instrs/query inst. of 4.
//   per feature (10 ops): 3 cndmask coef-half select +
//     acc = fma(A, fma(W',B,X'), fma(Y',B,acc))
//   asum (h=0 lanes) + bsum via __shfl_xor(acc,32);
//   out = asum * tanh(bsum) * exp(scale) + bias
// ---------------------------------------------------------------------------
__global__ __launch_bounds__(TPB) void query_kernel(
        const uint32_t* __restrict__ qcodes,
        const f32x4* __restrict__ coef,
        const float* __restrict__ scale,
        const float* __restrict__ bias,
        const int* __restrict__ idx0,
        const int* __restrict__ idx1,
        float* __restrict__ out, int N) {
    int t    = threadIdx.x;
    int lane = t & 63;
    int wid  = t >> 6;
    int q    = lane & 31;            // query slot within wave
    int h    = lane >> 5;            // feature-half this lane owns

    int qi = blockIdx.x * (TPB / 64 * 32) + wid * 32 + q;
    int m  = qi < N ? qi : N - 1;

    int r0 = idx0[m];
    int r1 = DIM0 + idx1[m];

    // one 16B load per row: half h of each row; pair lanes share the line
    u32x4 va = *((const u32x4*)(qcodes + (size_t)r0 * 8) + h);
    u32x4 vb = *((const u32x4*)(qcodes + (size_t)r1 * 8) + h);
    uint32_t aw[4] = {va.x, va.y, va.z, va.w};
    uint32_t bw[4] = {vb.x, vb.y, vb.z, vb.w};

    bool hi = (h != 0);
    float acc = 0.0f;
#pragma unroll
    for (int wd = 0; wd < 4; ++wd) {
        uint32_t wa = aw[wd];
        uint32_t wb = bw[wd];
#pragma unroll
        for (int j = 0; j < 8; ++j) {
            int f = wd * 8 + j;                  // 0..31 within the half
            f32x4 cA = coef[f];                  // uniform -> s_load
            f32x4 cB = coef[32 + f];             // uniform -> s_load
            float Wp = hi ? cB.x : cA.x;         // v_cndmask
            float Xp = hi ? cB.y : cA.y;
            float Yp = hi ? cB.z : cA.z;
            float A = (float)((wa >> (4 * j)) & 15u);
            float B = (float)((wb >> (4 * j)) & 15u);
            acc = fmaf(A, fmaf(Wp, B, Xp), fmaf(Yp, B, acc));
        }
    }

    const float* cs = (const float*)coef;
    float Ca = cs[NF * 4 + 0];
    float Cb = cs[NF * 4 + 1];
    acc += hi ? Cb : Ca;

    float other = __shfl_xor(acc, 32);           // partner half's sum
    if (h == 0 && qi < N) {
        float es = expf(scale[0]);
        float bi2 = bias[0];
        __builtin_nontemporal_store(acc * tanhf(other) * es + bi2, out + qi);
    }
}

extern "C" void kernel_launch(void* const* d_in, const int* in_sizes, int n_in,
                              void* d_out, int out_size, void* d_ws, size_t ws_size,
                              hipStream_t stream) {
    const float* values = (const float*)d_in[0];  // [1,4,64]
    const float* feats  = (const float*)d_in[1];  // [100000,64]
    const float* scale  = (const float*)d_in[3];  // [1]
    const float* bias   = (const float*)d_in[4];  // [1]
    const int*   idx0   = (const int*)d_in[5];    // [N]
    const int*   idx1   = (const int*)d_in[6];    // [N]
    float*       out    = (float*)d_out;          // [N] f32

    uint32_t* qcodes = (uint32_t*)d_ws;                          // 3.2 MB
    float*    coef   = (float*)((char*)d_ws + COEF_OFF_BYTES);   // 258 floats

    int nwords = SROWS * 8;                       // 800000 = 3125 * 256 exact
    quantize_kernel<<<nwords / TPB, TPB, 0, stream>>>(feats, values, qcodes, coef);

    int N = out_size;
    int qpb = TPB / 64 * 32;                      // 128 queries per block
    int qblocks = (N + qpb - 1) / qpb;
    query_kernel<<<qblocks, TPB, 0, stream>>>(
        qcodes, (const f32x4*)coef, scale, bias, idx0, idx1, out, N);
}